// Round 3
// baseline (85.415 us; speedup 1.0000x reference)
//
#include <hip/hip_runtime.h>

// Fully fused SMFNet. N=8192, D=64. chord mask = diag + wrapped superdiag, so
// W@V == V_new[i] = a_i*V[i] + b_i*V[(i+1)%N]. One block = 16 output rows;
// 20 context rows for V0, 17 for V1, 16 outputs (neighbor chain).
// R5 (= R4 with compile fix): DPP ctrl/rowmask must be template constants.
//  - V0 = H@g1 broadcast via LDS uniform-address ds_read_b128 (DS pipe)
//    instead of 320 v_readlane (VALU). Bit-identical fma order.
//  - wave_sum uses the canonical 6-step DPP reduce (row_ror x4, row_bcast15,
//    row_bcast31, one readlane) -- commuted-only association, bit-identical.
//  - ALL global loads (g pair, f pair, fL rows for both layers) issued at
//    kernel entry into registers; f-stage barrier gap is now just 8 ds_writes.
//  - T0 and T1 computed in ONE dual-accumulator matmul sharing X s_loads.

#define NROWS 8192
#define BROWS 16   // output rows per block
#define RPW 5      // rows per wave (4 waves * 5 = 20 context rows)

__device__ __forceinline__ float rl(float v, int lane) {
  return __int_as_float(__builtin_amdgcn_readlane(__float_as_int(v), lane));
}

template <int CTRL, int ROWMASK>
__device__ __forceinline__ float dppadd(float x) {
  return __int_as_float(__builtin_amdgcn_update_dpp(
      0, __float_as_int(x), CTRL, ROWMASK, 0xF, false));
}

// full-wave (64 lane) sum -> returned as wave-uniform value.
// row_ror 1/2/4/8 gives every lane its 16-row's sum; row_bcast15 (rows 1,3)
// then row_bcast31 (rows 2,3) accumulate cross-row; lane 63 holds the total.
__device__ __forceinline__ float wave_sum(float x) {
  x += dppadd<0x121, 0xF>(x);   // row_ror:1
  x += dppadd<0x122, 0xF>(x);   // row_ror:2
  x += dppadd<0x124, 0xF>(x);   // row_ror:4
  x += dppadd<0x128, 0xF>(x);   // row_ror:8
  x += dppadd<0x142, 0xA>(x);   // row_bcast15 -> rows 1,3
  x += dppadd<0x143, 0xC>(x);   // row_bcast31 -> rows 2,3
  return rl(x, 63);
}

// acc[r] = relu(sum_k X[growu[r]][k]*W[lane][k] + bias); A via scalar loads.
template <int R>
__device__ __forceinline__ void mm64_s(const float4 (*Wq)[65], int lane,
                                       const float* __restrict__ X,
                                       const int* growu, float bias, float* acc) {
#pragma unroll
  for (int r = 0; r < R; ++r) acc[r] = bias;
#pragma unroll 4
  for (int kb = 0; kb < 16; ++kb) {
    float4 w4 = Wq[kb][lane];             // ds_read_b128, lane-contiguous
#pragma unroll
    for (int r = 0; r < R; ++r) {
      float4 xq = *(const float4*)(X + (growu[r] << 6) + (kb << 2));  // s_load
      acc[r] = fmaf(xq.x, w4.x, acc[r]);
      acc[r] = fmaf(xq.y, w4.y, acc[r]);
      acc[r] = fmaf(xq.z, w4.z, acc[r]);
      acc[r] = fmaf(xq.w, w4.w, acc[r]);
    }
  }
#pragma unroll
  for (int r = 0; r < R; ++r) acc[r] = fmaxf(acc[r], 0.0f);
}

// dual-output variant: two weight matrices share the X s_loads.
template <int R>
__device__ __forceinline__ void mm64_x2(const float4 (*W0)[65], const float4 (*W1)[65],
                                        int lane, const float* __restrict__ X,
                                        const int* growu, float b0, float b1,
                                        float* a0, float* a1) {
#pragma unroll
  for (int r = 0; r < R; ++r) { a0[r] = b0; a1[r] = b1; }
#pragma unroll 4
  for (int kb = 0; kb < 16; ++kb) {
    float4 w0 = W0[kb][lane];
    float4 w1 = W1[kb][lane];
#pragma unroll
    for (int r = 0; r < R; ++r) {
      float4 xq = *(const float4*)(X + (growu[r] << 6) + (kb << 2));  // s_load
      a0[r] = fmaf(xq.x, w0.x, a0[r]);
      a0[r] = fmaf(xq.y, w0.y, a0[r]);
      a0[r] = fmaf(xq.z, w0.z, a0[r]);
      a0[r] = fmaf(xq.w, w0.w, a0[r]);
      a1[r] = fmaf(xq.x, w1.x, a1[r]);
      a1[r] = fmaf(xq.y, w1.y, a1[r]);
      a1[r] = fmaf(xq.z, w1.z, a1[r]);
      a1[r] = fmaf(xq.w, w1.w, a1[r]);
    }
  }
#pragma unroll
  for (int r = 0; r < R; ++r) {
    a0[r] = fmaxf(a0[r], 0.0f);
    a1[r] = fmaxf(a1[r], 0.0f);
  }
}

// A = H resident in LDS (wave-private rows): broadcast via uniform-address
// ds_read_b128 (DS pipe), zero v_readlane. fma order identical.
template <int R>
__device__ __forceinline__ void mm64_h(const float4 (*Wq)[65], int lane,
                                       const float (*Hrow)[64], float bias, float* acc) {
#pragma unroll
  for (int r = 0; r < R; ++r) acc[r] = bias;
#pragma unroll 4
  for (int kb = 0; kb < 16; ++kb) {
    float4 w4 = Wq[kb][lane];
#pragma unroll
    for (int r = 0; r < R; ++r) {
      float4 hq = *(const float4*)(&Hrow[r][kb << 2]);  // uniform addr -> bcast
      acc[r] = fmaf(hq.x, w4.x, acc[r]);
      acc[r] = fmaf(hq.y, w4.y, acc[r]);
      acc[r] = fmaf(hq.z, w4.z, acc[r]);
      acc[r] = fmaf(hq.w, w4.w, acc[r]);
    }
  }
#pragma unroll
  for (int r = 0; r < R; ++r) acc[r] = fmaxf(acc[r], 0.0f);
}

__global__ __launch_bounds__(256, 2) void fused_smfnet(
    const float* __restrict__ X, const float* __restrict__ g_w,
    const float* __restrict__ g_b, const float* __restrict__ f0_w,
    const float* __restrict__ f0_b, const float* __restrict__ fL_w,
    const float* __restrict__ fL_b, float* __restrict__ out)
{
  __shared__ float4 Wq[2][16][65];              // 33.3 KB, k-chunked weights
  __shared__ float V0s[20][65];                 // 5.2 KB
  __shared__ float V1s[17][65];                 // 4.4 KB
  __shared__ __align__(16) float Hs[4][RPW][64];// 5.1 KB (uniform-addr reads)

  const int tid  = threadIdx.x;
  const int lane = tid & 63;
  const int wv   = tid >> 6;                 // wave id 0..3
  const int r0   = blockIdx.x * BROWS;

  // ---- entry: issue ALL global loads up front (g first: critical path) ----
  const float4* gq = (const float4*)g_w;
  float4 gw[8];
#pragma unroll
  for (int p = 0; p < 8; ++p) gw[p] = gq[p * 256 + tid];     // g0+g1

  int growu[RPW];                            // wave-uniform (SGPR) row indices
#pragma unroll
  for (int r = 0; r < RPW; ++r)
    growu[r] = __builtin_amdgcn_readfirstlane((r0 + wv * RPW + r) & (NROWS - 1));

  const float* fw1 = fL_w + NROWS * 64;
  float fa0[RPW], fb0[RPW], fa1[RPW], fb1v[RPW];  // fL rows, both layers
#pragma unroll
  for (int r = 0; r < RPW; ++r) {
    int g = growu[r], gp1 = (g + 1) & (NROWS - 1);
    fa0[r]  = fL_w[g * 64 + lane];
    fb0[r]  = fL_w[gp1 * 64 + lane];
    fa1[r]  = fw1[g * 64 + lane];
    fb1v[r] = fw1[gp1 * 64 + lane];
  }

  const float4* fq = (const float4*)f0_w;
  float4 fw[8];
#pragma unroll
  for (int p = 0; p < 8; ++p) fw[p] = fq[p * 256 + tid];     // f00+f01

  // write g pair to LDS (waits only on gw: issued first in the VMEM queue)
#pragma unroll
  for (int p = 0; p < 8; ++p) {
    int idx = p * 256 + tid, rem = idx & 1023;
    Wq[idx >> 10][rem & 15][rem >> 4] = gw[p];
  }
  float hb = g_b[lane], vb = g_b[64 + lane];
  __syncthreads();                           // A: g staged

  float h[RPW];
  mm64_s<RPW>(Wq[0], lane, X, growu, hb, h); // H = relu(X @ g0^T + b0)
#pragma unroll
  for (int r = 0; r < RPW; ++r) Hs[wv][r][lane] = h[r];   // wave-private

  float v0[RPW];
  mm64_h<RPW>(Wq[1], lane, Hs[wv], vb, v0);  // V0 = relu(H @ g1^T + b1)
#pragma unroll
  for (int r = 0; r < RPW; ++r) V0s[wv * RPW + r][lane] = v0[r];
  __syncthreads();                           // B: V0s visible, Wq free

#pragma unroll
  for (int p = 0; p < 8; ++p) {              // f pair regs -> LDS (no latency)
    int idx = p * 256 + tid, rem = idx & 1023;
    Wq[idx >> 10][rem & 15][rem >> 4] = fw[p];
  }
  __syncthreads();                           // C: f staged

  float t0[RPW], t1[RPW];
  mm64_x2<RPW>(Wq[0], Wq[1], lane, X, growu,
               f0_b[lane], f0_b[64 + lane], t0, t1);  // T0, T1 fused

  float v1[RPW];
#pragma unroll
  for (int r = 0; r < RPW; ++r) {
    int L = wv * RPW + r;
    if (L <= 16) {                           // wave-uniform predicate
      int g = growu[r], gp1 = (g + 1) & (NROWS - 1);
      float pa = wave_sum(t0[r] * fa0[r]);
      float pb = wave_sum(t0[r] * fb0[r]);
      float a  = fmaxf(pa + fL_b[g], 0.0f);
      float b  = fmaxf(pb + fL_b[gp1], 0.0f);
      v1[r] = a * v0[r] + b * V0s[L + 1][lane];
      V1s[L][lane] = v1[r];
    }
  }
  __syncthreads();                           // D: V1s visible

  const float* fb1 = fL_b + NROWS;
#pragma unroll
  for (int r = 0; r < RPW; ++r) {
    int L = wv * RPW + r;
    if (L <= 15) {
      int g = growu[r], gp1 = (g + 1) & (NROWS - 1);
      float pa = wave_sum(t1[r] * fa1[r]);
      float pb = wave_sum(t1[r] * fb1v[r]);
      float a  = fmaxf(pa + fb1[g], 0.0f);
      float b  = fmaxf(pb + fb1[gp1], 0.0f);
      out[g * 64 + lane] = a * v1[r] + b * V1s[L + 1][lane];
    }
  }
}

extern "C" void kernel_launch(void* const* d_in, const int* in_sizes, int n_in,
                              void* d_out, int out_size, void* d_ws, size_t ws_size,
                              hipStream_t stream) {
  const float* X    = (const float*)d_in[0];  // [8192,64]
  const float* g_w  = (const float*)d_in[1];  // [2,64,64]
  const float* g_b  = (const float*)d_in[2];  // [2,64]
  const float* f0_w = (const float*)d_in[3];  // [2,64,64]
  const float* f0_b = (const float*)d_in[4];  // [2,64]
  const float* fL_w = (const float*)d_in[5];  // [2,8192,64]
  const float* fL_b = (const float*)d_in[6];  // [2,8192]
  float* out = (float*)d_out;                 // [8192,64] fp32

  fused_smfnet<<<dim3(NROWS / BROWS), dim3(256), 0, stream>>>(
      X, g_w, g_b, f0_w, f0_b, fL_w, fL_b, out);
}